// Round 4
// baseline (209.781 us; speedup 1.0000x reference)
//
#include <hip/hip_runtime.h>

// Fused 3D local-NCC loss. Shapes (2,1,160,192,160) fp32,
// flat = ((n*D + d)*H + h)*W + w. 9x9x9 box window, zero-padded.
//
// v4: 32(w) x 16(h) x 28(d) tile per block, 36-plane D-march.
// Per plane, 3 phases (2 LDS-only barriers):
//   A  (192 thr): consume prefetched I/J rows -> products -> register 9-tap
//      W-slide -> b128 write to double-buffered ws; then issue next plane's
//      global loads (they stay in flight across the lgkm-only barriers).
//   A2 (320 thr): sliding 9-tap H-sum of ws columns -> hw (5ch x 16h x 32w).
//   B  (512 thr): 5 LDS reads -> D sliding window (9-deep static ring) -> cc.
// Barriers are s_waitcnt lgkmcnt(0) + s_barrier (no vmcnt drain).

namespace {
constexpr int Wd = 160, Hd = 192, Dd = 160, NB = 2;
constexpr long DSTRIDE = (long)Hd * Wd;        // 30720
constexpr long VOLUME  = (long)Dd * DSTRIDE;   // 4,915,200
constexpr long TOTAL   = VOLUME * NB;          // 9,830,400
constexpr int BW = 32, BH = 16, BD = 28;
constexpr int EH = BH + 8;                     // 24 halo rows
constexpr int NWB = 5, NHB = 12, NDB = 6;      // 6*28=168 covers 160
constexpr int NBLK = NB * NDB * NHB * NWB;     // 720
constexpr int NT = 512;
constexpr int CH  = EH * BW;                   // 768 floats / channel (ws)
constexpr int HWC = BH * BW;                   // 512 floats / channel (hw)
constexpr float INV_WV = 1.0f / 729.0f;
}

__device__ __forceinline__ void bar_lds() {
    asm volatile("s_waitcnt lgkmcnt(0)\n\ts_barrier" ::: "memory");
}

__global__ __launch_bounds__(NT) void k_ncc(const float* __restrict__ I,
                                            const float* __restrict__ J,
                                            float* __restrict__ partial) {
    __shared__ float ws[2][5 * CH];   // 30,720 B
    __shared__ float hw[5 * HWC];     // 10,240 B
    __shared__ float red[NT];         //  2,048 B

    const int tid = threadIdx.x;
    int bx = blockIdx.x;
    const int wb = bx % NWB; bx /= NWB;
    const int hb = bx % NHB; bx /= NHB;
    const int db = bx % NDB; bx /= NDB;
    const int n  = bx;
    const int w0 = wb * BW, h0 = hb * BH, d0 = db * BD;
    const long nvol = (long)n * VOLUME;

    // ---- Phase-A mapping (tid < 192): 24 rows x 8 four-wide segments ----
    const int seg = tid & 7;
    const int yy  = tid >> 3;
    const bool aJob = (tid < 192);
    const int ah    = h0 - 4 + yy;
    const int wbase = w0 - 4 + (seg << 2);
    const bool ahOk = aJob && ((unsigned)ah < (unsigned)Hd);
    bool qok[3];
#pragma unroll
    for (int q = 0; q < 3; ++q)
        qok[q] = ((unsigned)(wbase + 4 * q) < (unsigned)Wd);
    // Prefetch pointers, start at plane d0-4 (advanced by DSTRIDE per issue).
    const long roff = nvol + (long)ah * Wd + wbase + (long)(d0 - 4) * DSTRIDE;
    const float* aI = I + roff;
    const float* aJ = J + roff;

    // ---- Phase-A2 mapping (tid < 320): c = tid>>6, half = (tid>>5)&1 ----
    const int c2 = tid >> 6;
    const int h2 = (tid >> 5) & 1;
    const int w2 = tid & 31;
    const int ho0 = h2 * 8;

    // ---- Phase-B mapping ----
    const int tx = tid & 31, ty = tid >> 5;

    float vi[12], vj[12];
    auto issue = [&](int p) {
        const bool pv = ((unsigned)p < (unsigned)Dd);
        if (aJob) {
            if (pv && ahOk) {
#pragma unroll
                for (int q = 0; q < 3; ++q) {
                    float4 a = qok[q] ? *(const float4*)(aI + 4 * q) : float4{0, 0, 0, 0};
                    float4 b = qok[q] ? *(const float4*)(aJ + 4 * q) : float4{0, 0, 0, 0};
                    vi[4 * q] = a.x; vi[4 * q + 1] = a.y; vi[4 * q + 2] = a.z; vi[4 * q + 3] = a.w;
                    vj[4 * q] = b.x; vj[4 * q + 1] = b.y; vj[4 * q + 2] = b.z; vj[4 * q + 3] = b.w;
                }
            } else {
#pragma unroll
                for (int i = 0; i < 12; ++i) { vi[i] = 0.0f; vj[i] = 0.0f; }
            }
        }
    };

    float hist[9][5];
#pragma unroll
    for (int k = 0; k < 9; ++k)
#pragma unroll
        for (int c = 0; c < 5; ++c) hist[k][c] = 0.0f;
    float sa[5] = {0, 0, 0, 0, 0};
    float acc = 0.0f;

    issue(d0 - 4);   // prime prefetch

#pragma unroll 1
    for (int M = 0; M < 4; ++M) {
#pragma unroll
        for (int u = 0; u < 9; ++u) {
            const int t = 9 * M + u;
            const int p = d0 - 4 + t;
            const bool pvalid = ((unsigned)p < (unsigned)Dd);
            float* const wsp = ws[t & 1];

            // ---------- Phase A: consume prefetch -> W-slide -> LDS ------
            if (pvalid && aJob) {
                float* const wab = wsp + yy * BW + (seg << 2);
#pragma unroll
                for (int c = 0; c < 5; ++c) {
                    float v[12];
#pragma unroll
                    for (int i = 0; i < 12; ++i) {
                        v[i] = (c == 0) ? vi[i]
                             : (c == 1) ? vj[i]
                             : (c == 2) ? vi[i] * vi[i]
                             : (c == 3) ? vj[i] * vj[i]
                                        : vi[i] * vj[i];
                    }
                    float s8 = ((v[0] + v[1]) + (v[2] + v[3]))
                             + ((v[4] + v[5]) + (v[6] + v[7])) + v[8];
                    float4 o;
                    o.x = s8;
                    o.y = o.x + (v[9]  - v[0]);
                    o.z = o.y + (v[10] - v[1]);
                    o.w = o.z + (v[11] - v[2]);
                    *(float4*)(wab + c * CH) = o;
                }
            }
            // Issue next plane's loads; they remain in flight across the
            // lgkm-only barriers below.
            aI += DSTRIDE; aJ += DSTRIDE;
            issue(p + 1);

            bar_lds();

            // ---------- Phase A2: sliding 9-tap H-sum -> hw --------------
            if (pvalid && tid < 320) {
                const float* const src = wsp + c2 * CH + ho0 * BW + w2;
                float* const dst = hw + c2 * HWC + ho0 * BW + w2;
                float s = ((src[0 * BW] + src[1 * BW]) + (src[2 * BW] + src[3 * BW]))
                        + ((src[4 * BW] + src[5 * BW]) + (src[6 * BW] + src[7 * BW]));
#pragma unroll
                for (int k = 0; k < 8; ++k) {
                    s += src[(k + 8) * BW];
                    dst[k * BW] = s;
                    s -= src[k * BW];
                }
            }

            bar_lds();

            // ---------- Phase B: 5 reads + D-window + cc -----------------
            float h5[5];
            if (pvalid) {
#pragma unroll
                for (int c = 0; c < 5; ++c)
                    h5[c] = hw[c * HWC + ty * BW + tx];
            } else {
#pragma unroll
                for (int c = 0; c < 5; ++c) h5[c] = 0.0f;
            }
#pragma unroll
            for (int c = 0; c < 5; ++c) sa[c] += h5[c];
            const int dout = d0 + t - 8;
            if (t >= 8 && dout < Dd) {
                const float cross = sa[4] - sa[0] * sa[1] * INV_WV;
                const float iv    = sa[2] - sa[0] * sa[0] * INV_WV;
                const float jv    = sa[3] - sa[1] * sa[1] * INV_WV;
                acc += (cross * cross) * __builtin_amdgcn_rcpf(iv * jv + 1e-5f);
            }
#pragma unroll
            for (int c = 0; c < 5; ++c) sa[c] -= hist[(u + 1) % 9][c];
#pragma unroll
            for (int c = 0; c < 5; ++c) hist[u][c] = h5[c];
        }
    }

    // ---- block reduction ----
    red[tid] = acc;
    __syncthreads();
    for (int off = NT / 2; off > 0; off >>= 1) {
        if (tid < off) red[tid] += red[tid + off];
        __syncthreads();
    }
    if (tid == 0) partial[blockIdx.x] = red[0];
}

__global__ __launch_bounds__(256) void k_final(const float* __restrict__ partial,
                                               float* __restrict__ out, int nparts) {
    __shared__ double red[256];
    double a = 0.0;
    for (int i = threadIdx.x; i < nparts; i += 256) a += (double)partial[i];
    red[threadIdx.x] = a;
    __syncthreads();
    for (int off = 128; off > 0; off >>= 1) {
        if (threadIdx.x < off) red[threadIdx.x] += red[threadIdx.x + off];
        __syncthreads();
    }
    if (threadIdx.x == 0) out[0] = (float)(-red[0] / (double)TOTAL);
}

extern "C" void kernel_launch(void* const* d_in, const int* in_sizes, int n_in,
                              void* d_out, int out_size, void* d_ws, size_t ws_size,
                              hipStream_t stream) {
    const float* I = (const float*)d_in[0];
    const float* J = (const float*)d_in[1];
    float* partial = (float*)d_ws;          // NBLK floats = 2.88 KB
    float* out = (float*)d_out;

    k_ncc<<<NBLK, NT, 0, stream>>>(I, J, partial);
    k_final<<<1, 256, 0, stream>>>(partial, out, NBLK);
}

// Round 5
// 161.498 us; speedup vs baseline: 1.2990x; 1.2990x over previous
//
#include <hip/hip_runtime.h>

// Fused 3D local-NCC loss. Shapes (2,1,160,192,160) fp32,
// flat = ((n*D + d)*H + h)*W + w. 9x9x9 box window, zero-padded.
//
// v5: 32(w) x 16(h) x 28(d) tile per block, 36-plane D-march.
// Per plane, 3 phases split by LDS-only barriers (no vmcnt drain):
//   A  (192 thr): consume prefetched I/J rows (held in explicit float4
//      SCALARS -- spill-proof) -> products -> register 9-tap W-slide ->
//      b128 write to ws; then issue next plane's loads (stay in flight
//      across both barriers).
//   A2 (320 thr): sliding 9-tap H-sum of ws columns -> hw (5ch x 16 x 32).
//   B  (512 thr): 5 LDS reads -> D sliding window (static 9-ring) -> cc.

namespace {
constexpr int Wd = 160, Hd = 192, Dd = 160, NB = 2;
constexpr long DSTRIDE = (long)Hd * Wd;        // 30720
constexpr long VOLUME  = (long)Dd * DSTRIDE;   // 4,915,200
constexpr long TOTAL   = VOLUME * NB;          // 9,830,400
constexpr int BW = 32, BH = 16, BD = 28;
constexpr int EH = BH + 8;                     // 24 halo rows
constexpr int NWB = 5, NHB = 12, NDB = 6;      // 6*28=168 covers 160
constexpr int NBLK = NB * NDB * NHB * NWB;     // 720
constexpr int NT = 512;
constexpr int CH  = EH * BW;                   // 768 floats / channel (ws)
constexpr int HWC = BH * BW;                   // 512 floats / channel (hw)
constexpr float INV_WV = 1.0f / 729.0f;
}

__device__ __forceinline__ void bar_lds() {
    asm volatile("s_waitcnt lgkmcnt(0)\n\ts_barrier" ::: "memory");
}

__device__ __forceinline__ float4 slide9(float v0, float v1, float v2, float v3,
                                         float v4, float v5, float v6, float v7,
                                         float v8, float v9, float v10, float v11) {
    float s8 = ((v0 + v1) + (v2 + v3)) + ((v4 + v5) + (v6 + v7)) + v8;
    float4 o;
    o.x = s8;
    o.y = o.x + (v9 - v0);
    o.z = o.y + (v10 - v1);
    o.w = o.z + (v11 - v2);
    return o;
}

__global__ __launch_bounds__(NT) void k_ncc(const float* __restrict__ I,
                                            const float* __restrict__ J,
                                            float* __restrict__ partial) {
    __shared__ float ws[5 * CH];    // 15,360 B (single buffer)
    __shared__ float hw[5 * HWC];   // 10,240 B
    __shared__ float red[NT];       //  2,048 B

    const int tid = threadIdx.x;
    int bx = blockIdx.x;
    const int wb = bx % NWB; bx /= NWB;
    const int hb = bx % NHB; bx /= NHB;
    const int db = bx % NDB; bx /= NDB;
    const int n  = bx;
    const int w0 = wb * BW, h0 = hb * BH, d0 = db * BD;
    const long nvol = (long)n * VOLUME;

    // ---- Phase-A mapping (tid < 192): 24 rows x 8 four-wide segments ----
    const int seg = tid & 7;
    const int yy  = tid >> 3;
    const bool aJob = (tid < 192);
    const int ah    = h0 - 4 + yy;
    const int wbase = w0 - 4 + (seg << 2);
    const bool ahOk = aJob && ((unsigned)ah < (unsigned)Hd);
    const bool qok0 = ((unsigned)(wbase + 0) < (unsigned)Wd);
    const bool qok1 = ((unsigned)(wbase + 4) < (unsigned)Wd);
    const bool qok2 = ((unsigned)(wbase + 8) < (unsigned)Wd);
    const long roff = nvol + (long)ah * Wd + wbase + (long)(d0 - 4) * DSTRIDE;
    const float* aI = I + roff;
    const float* aJ = J + roff;

    // ---- Phase-A2 mapping (tid < 320) ----
    const int c2  = tid >> 6;          // channel 0..4
    const int ho0 = ((tid >> 5) & 1) * 8;
    const int w2  = tid & 31;

    // ---- Phase-B mapping ----
    const int tx = tid & 31, ty = tid >> 5;

    // Prefetch registers (explicit scalars -> never spilled).
    float4 pI0, pI1, pI2, pJ0, pJ1, pJ2;

#define ISSUE(PP)                                                            \
    do {                                                                     \
        const bool _pv = ahOk && ((unsigned)(PP) < (unsigned)Dd);            \
        pI0 = (_pv && qok0) ? *(const float4*)(aI + 0) : float4{0, 0, 0, 0}; \
        pI1 = (_pv && qok1) ? *(const float4*)(aI + 4) : float4{0, 0, 0, 0}; \
        pI2 = (_pv && qok2) ? *(const float4*)(aI + 8) : float4{0, 0, 0, 0}; \
        pJ0 = (_pv && qok0) ? *(const float4*)(aJ + 0) : float4{0, 0, 0, 0}; \
        pJ1 = (_pv && qok1) ? *(const float4*)(aJ + 4) : float4{0, 0, 0, 0}; \
        pJ2 = (_pv && qok2) ? *(const float4*)(aJ + 8) : float4{0, 0, 0, 0}; \
    } while (0)

    float hist[9][5];
#pragma unroll
    for (int k = 0; k < 9; ++k)
#pragma unroll
        for (int c = 0; c < 5; ++c) hist[k][c] = 0.0f;
    float sa[5] = {0, 0, 0, 0, 0};
    float acc = 0.0f;

    ISSUE(d0 - 4);   // prime

#pragma unroll 1
    for (int M = 0; M < 4; ++M) {
#pragma unroll
        for (int u = 0; u < 9; ++u) {
            const int t = 9 * M + u;
            const int p = d0 - 4 + t;
            const bool pvalid = ((unsigned)p < (unsigned)Dd);

            // ---------- Phase A: consume prefetch -> W-slide -> LDS ------
            if (pvalid && aJob) {
                const float a0 = pI0.x, a1 = pI0.y, a2 = pI0.z, a3 = pI0.w;
                const float a4 = pI1.x, a5 = pI1.y, a6 = pI1.z, a7 = pI1.w;
                const float a8 = pI2.x, a9 = pI2.y, a10 = pI2.z, a11 = pI2.w;
                const float b0 = pJ0.x, b1 = pJ0.y, b2 = pJ0.z, b3 = pJ0.w;
                const float b4 = pJ1.x, b5 = pJ1.y, b6 = pJ1.z, b7 = pJ1.w;
                const float b8 = pJ2.x, b9 = pJ2.y, b10 = pJ2.z, b11 = pJ2.w;
                float* const wab = ws + yy * BW + (seg << 2);
                *(float4*)(wab + 0 * CH) =
                    slide9(a0, a1, a2, a3, a4, a5, a6, a7, a8, a9, a10, a11);
                *(float4*)(wab + 1 * CH) =
                    slide9(b0, b1, b2, b3, b4, b5, b6, b7, b8, b9, b10, b11);
                *(float4*)(wab + 2 * CH) =
                    slide9(a0 * a0, a1 * a1, a2 * a2, a3 * a3, a4 * a4, a5 * a5,
                           a6 * a6, a7 * a7, a8 * a8, a9 * a9, a10 * a10, a11 * a11);
                *(float4*)(wab + 3 * CH) =
                    slide9(b0 * b0, b1 * b1, b2 * b2, b3 * b3, b4 * b4, b5 * b5,
                           b6 * b6, b7 * b7, b8 * b8, b9 * b9, b10 * b10, b11 * b11);
                *(float4*)(wab + 4 * CH) =
                    slide9(a0 * b0, a1 * b1, a2 * b2, a3 * b3, a4 * b4, a5 * b5,
                           a6 * b6, a7 * b7, a8 * b8, a9 * b9, a10 * b10, a11 * b11);
            }
            // Issue next plane's loads (in flight across both barriers).
            aI += DSTRIDE; aJ += DSTRIDE;
            ISSUE(p + 1);

            bar_lds();

            // ---------- Phase A2: sliding 9-tap H-sum -> hw --------------
            if (pvalid && tid < 320) {
                const float* const src = ws + c2 * CH + ho0 * BW + w2;
                float* const dst = hw + c2 * HWC + ho0 * BW + w2;
                float s = ((src[0 * BW] + src[1 * BW]) + (src[2 * BW] + src[3 * BW]))
                        + ((src[4 * BW] + src[5 * BW]) + (src[6 * BW] + src[7 * BW]));
#pragma unroll
                for (int k = 0; k < 8; ++k) {
                    s += src[(k + 8) * BW];
                    dst[k * BW] = s;
                    s -= src[k * BW];
                }
            }

            bar_lds();

            // ---------- Phase B: 5 reads + D-window + cc -----------------
            float h5[5];
            if (pvalid) {
#pragma unroll
                for (int c = 0; c < 5; ++c)
                    h5[c] = hw[c * HWC + ty * BW + tx];
            } else {
#pragma unroll
                for (int c = 0; c < 5; ++c) h5[c] = 0.0f;
            }
#pragma unroll
            for (int c = 0; c < 5; ++c) sa[c] += h5[c];
            const int dout = d0 + t - 8;
            if (t >= 8 && dout < Dd) {
                const float cross = sa[4] - sa[0] * sa[1] * INV_WV;
                const float iv    = sa[2] - sa[0] * sa[0] * INV_WV;
                const float jv    = sa[3] - sa[1] * sa[1] * INV_WV;
                acc += (cross * cross) * __builtin_amdgcn_rcpf(iv * jv + 1e-5f);
            }
#pragma unroll
            for (int c = 0; c < 5; ++c) sa[c] -= hist[(u + 1) % 9][c];
#pragma unroll
            for (int c = 0; c < 5; ++c) hist[u][c] = h5[c];
        }
    }
#undef ISSUE

    // ---- block reduction ----
    red[tid] = acc;
    __syncthreads();
    for (int off = NT / 2; off > 0; off >>= 1) {
        if (tid < off) red[tid] += red[tid + off];
        __syncthreads();
    }
    if (tid == 0) partial[blockIdx.x] = red[0];
}

__global__ __launch_bounds__(256) void k_final(const float* __restrict__ partial,
                                               float* __restrict__ out, int nparts) {
    __shared__ double red[256];
    double a = 0.0;
    for (int i = threadIdx.x; i < nparts; i += 256) a += (double)partial[i];
    red[threadIdx.x] = a;
    __syncthreads();
    for (int off = 128; off > 0; off >>= 1) {
        if (threadIdx.x < off) red[threadIdx.x] += red[threadIdx.x + off];
        __syncthreads();
    }
    if (threadIdx.x == 0) out[0] = (float)(-red[0] / (double)TOTAL);
}

extern "C" void kernel_launch(void* const* d_in, const int* in_sizes, int n_in,
                              void* d_out, int out_size, void* d_ws, size_t ws_size,
                              hipStream_t stream) {
    const float* I = (const float*)d_in[0];
    const float* J = (const float*)d_in[1];
    float* partial = (float*)d_ws;          // NBLK floats = 2.88 KB
    float* out = (float*)d_out;

    k_ncc<<<NBLK, NT, 0, stream>>>(I, J, partial);
    k_final<<<1, 256, 0, stream>>>(partial, out, NBLK);
}

// Round 6
// 161.409 us; speedup vs baseline: 1.2997x; 1.0006x over previous
//
#include <hip/hip_runtime.h>

// Fused 3D local-NCC loss. Shapes (2,1,160,192,160) fp32,
// flat = ((n*D + d)*H + h)*W + w. 9x9x9 box window, zero-padded.
//
// v6: 32(w) x 16(h) x 28(d) tile, 38-iteration skewed pipeline with ONE
// lgkm-only barrier per iteration. Stage A (plane t): prefetched I/J rows
// in float4 scalars -> register 9-tap W-slide -> ws[t&1]. Stage A2
// (plane t-1): cooperative sliding 9-tap H-sum ws->hw[(t-1)&1]. Stage B
// (plane t-2): 5 LDS reads -> 9-deep static D-ring -> cc. Opposite buffer
// parities per iteration => no intra-iteration hazards; the single barrier
// orders cross-iteration reuse. Block partials -> pre-scaled atomicAdd.

namespace {
constexpr int Wd = 160, Hd = 192, Dd = 160, NB = 2;
constexpr long DSTRIDE = (long)Hd * Wd;        // 30720
constexpr long VOLUME  = (long)Dd * DSTRIDE;   // 4,915,200
constexpr long TOTAL   = VOLUME * NB;          // 9,830,400
constexpr int BW = 32, BH = 16, BD = 28;
constexpr int EH = BH + 8;                     // 24 halo rows
constexpr int NWB = 5, NHB = 12, NDB = 6;      // 6*28=168 covers 160
constexpr int NBLK = NB * NDB * NHB * NWB;     // 720
constexpr int NT = 512;
constexpr int CH  = EH * BW;                   // 768 floats / channel (ws)
constexpr int HWC = BH * BW;                   // 512 floats / channel (hw)
constexpr float INV_WV = 1.0f / 729.0f;
constexpr float NEG_INV_TOTAL = -1.0f / 9830400.0f;
}

__device__ __forceinline__ void bar_lds() {
    asm volatile("s_waitcnt lgkmcnt(0)\n\ts_barrier" ::: "memory");
}

__device__ __forceinline__ float4 slide9(float v0, float v1, float v2, float v3,
                                         float v4, float v5, float v6, float v7,
                                         float v8, float v9, float v10, float v11) {
    float s8 = ((v0 + v1) + (v2 + v3)) + ((v4 + v5) + (v6 + v7)) + v8;
    float4 o;
    o.x = s8;
    o.y = o.x + (v9 - v0);
    o.z = o.y + (v10 - v1);
    o.w = o.z + (v11 - v2);
    return o;
}

__global__ __launch_bounds__(NT) void k_ncc(const float* __restrict__ I,
                                            const float* __restrict__ J,
                                            float* __restrict__ out) {
    __shared__ float ws[2][5 * CH];    // 30,720 B
    __shared__ float hw[2][5 * HWC];   // 20,480 B
    __shared__ float red[NT];          //  2,048 B

    const int tid = threadIdx.x;
    int bx = blockIdx.x;
    const int wb = bx % NWB; bx /= NWB;
    const int hb = bx % NHB; bx /= NHB;
    const int db = bx % NDB; bx /= NDB;
    const int n  = bx;
    const int w0 = wb * BW, h0 = hb * BH, d0 = db * BD;
    const long nvol = (long)n * VOLUME;

    // ---- Stage-A mapping (tid < 192): 24 rows x 8 four-wide segments ----
    const int seg = tid & 7;
    const int yy  = tid >> 3;
    const bool aJob = (tid < 192);
    const int ah    = h0 - 4 + yy;
    const int wbase = w0 - 4 + (seg << 2);
    const bool ahOk = aJob && ((unsigned)ah < (unsigned)Hd);
    const bool qok0 = ((unsigned)(wbase + 0) < (unsigned)Wd);
    const bool qok1 = ((unsigned)(wbase + 4) < (unsigned)Wd);
    const bool qok2 = ((unsigned)(wbase + 8) < (unsigned)Wd);
    const long roff = nvol + (long)ah * Wd + wbase + (long)(d0 - 4) * DSTRIDE;
    const float* aI = I + roff;
    const float* aJ = J + roff;

    // ---- Stage-A2 mapping (tid < 320) ----
    const int c2  = tid >> 6;
    const int ho0 = ((tid >> 5) & 1) * 8;
    const int w2  = tid & 31;

    // ---- Stage-B mapping ----
    const int tx = tid & 31, ty = tid >> 5;

    float4 pI0, pI1, pI2, pJ0, pJ1, pJ2;

#define ISSUE(PP)                                                            \
    do {                                                                     \
        const bool _pv = ahOk && ((unsigned)(PP) < (unsigned)Dd);            \
        pI0 = (_pv && qok0) ? *(const float4*)(aI + 0) : float4{0, 0, 0, 0}; \
        pI1 = (_pv && qok1) ? *(const float4*)(aI + 4) : float4{0, 0, 0, 0}; \
        pI2 = (_pv && qok2) ? *(const float4*)(aI + 8) : float4{0, 0, 0, 0}; \
        pJ0 = (_pv && qok0) ? *(const float4*)(aJ + 0) : float4{0, 0, 0, 0}; \
        pJ1 = (_pv && qok1) ? *(const float4*)(aJ + 4) : float4{0, 0, 0, 0}; \
        pJ2 = (_pv && qok2) ? *(const float4*)(aJ + 8) : float4{0, 0, 0, 0}; \
    } while (0)

#define STAGE_A(WSP, PV)                                                       \
    if ((PV) && aJob) {                                                        \
        const float a0 = pI0.x, a1 = pI0.y, a2 = pI0.z, a3 = pI0.w;            \
        const float a4 = pI1.x, a5 = pI1.y, a6 = pI1.z, a7 = pI1.w;            \
        const float a8 = pI2.x, a9 = pI2.y, a10 = pI2.z, a11 = pI2.w;          \
        const float b0 = pJ0.x, b1 = pJ0.y, b2 = pJ0.z, b3 = pJ0.w;            \
        const float b4 = pJ1.x, b5 = pJ1.y, b6 = pJ1.z, b7 = pJ1.w;            \
        const float b8 = pJ2.x, b9 = pJ2.y, b10 = pJ2.z, b11 = pJ2.w;          \
        float* const wab = (WSP) + yy * BW + (seg << 2);                       \
        *(float4*)(wab + 0 * CH) =                                             \
            slide9(a0, a1, a2, a3, a4, a5, a6, a7, a8, a9, a10, a11);          \
        *(float4*)(wab + 1 * CH) =                                             \
            slide9(b0, b1, b2, b3, b4, b5, b6, b7, b8, b9, b10, b11);          \
        *(float4*)(wab + 2 * CH) =                                             \
            slide9(a0 * a0, a1 * a1, a2 * a2, a3 * a3, a4 * a4, a5 * a5,       \
                   a6 * a6, a7 * a7, a8 * a8, a9 * a9, a10 * a10, a11 * a11);  \
        *(float4*)(wab + 3 * CH) =                                             \
            slide9(b0 * b0, b1 * b1, b2 * b2, b3 * b3, b4 * b4, b5 * b5,       \
                   b6 * b6, b7 * b7, b8 * b8, b9 * b9, b10 * b10, b11 * b11);  \
        *(float4*)(wab + 4 * CH) =                                             \
            slide9(a0 * b0, a1 * b1, a2 * b2, a3 * b3, a4 * b4, a5 * b5,       \
                   a6 * b6, a7 * b7, a8 * b8, a9 * b9, a10 * b10, a11 * b11);  \
    }

#define STAGE_A2(WSR, HWW, PV)                                                 \
    if ((PV) && tid < 320) {                                                   \
        const float* const src = (WSR) + c2 * CH + ho0 * BW + w2;              \
        float* const dst = (HWW) + c2 * HWC + ho0 * BW + w2;                   \
        float s = ((src[0 * BW] + src[1 * BW]) + (src[2 * BW] + src[3 * BW]))  \
                + ((src[4 * BW] + src[5 * BW]) + (src[6 * BW] + src[7 * BW])); \
        _Pragma("unroll")                                                      \
        for (int k = 0; k < 8; ++k) {                                          \
            s += src[(k + 8) * BW];                                            \
            dst[k * BW] = s;                                                   \
            s -= src[k * BW];                                                  \
        }                                                                      \
    }

    float hist[9][5];
#pragma unroll
    for (int k = 0; k < 9; ++k)
#pragma unroll
        for (int c = 0; c < 5; ++c) hist[k][c] = 0.0f;
    float sa[5] = {0, 0, 0, 0, 0};
    float acc = 0.0f;

    ISSUE(d0 - 4);   // prime

    // ---- peel k=0: A only (plane d0-4 -> ws[0]) ----
    {
        const int pA = d0 - 4;
        STAGE_A(ws[0], (unsigned)pA < (unsigned)Dd);
        aI += DSTRIDE; aJ += DSTRIDE;
        ISSUE(pA + 1);
        bar_lds();
    }
    // ---- peel k=1: A (plane d0-3 -> ws[1]); A2 (plane d0-4: ws[0]->hw[0])
    {
        const int pA = d0 - 3;
        STAGE_A(ws[1], (unsigned)pA < (unsigned)Dd);
        aI += DSTRIDE; aJ += DSTRIDE;
        ISSUE(pA + 1);
        STAGE_A2(ws[0], hw[0], (unsigned)(d0 - 4) < (unsigned)Dd);
        bar_lds();
    }

#pragma unroll 1
    for (int M = 0; M < 4; ++M) {
        const int mpar = M & 1;
#pragma unroll
        for (int u = 0; u < 9; ++u) {
            const int t   = 9 * M + u;       // B's plane offset (matches v5)
            const int pB  = d0 - 4 + t;
            const int pA2 = pB + 1;
            const int pA  = pB + 2;
            const int parA  = (mpar + u) & 1;
            const int parA2 = (mpar + u + 1) & 1;

            // Stage A: plane pA -> ws[parA]
            STAGE_A(ws[parA], (t <= 33) && ((unsigned)pA < (unsigned)Dd));
            aI += DSTRIDE; aJ += DSTRIDE;
            if (M < 3 || u <= 5) { ISSUE(pA + 1); }

            // Stage A2: plane pA2: ws[parA2] -> hw[parA2]
            STAGE_A2(ws[parA2], hw[parA2], (t <= 34) && ((unsigned)pA2 < (unsigned)Dd));

            // Stage B: plane pB from hw[parA] (written last iteration)
            float h5[5];
            if ((unsigned)pB < (unsigned)Dd) {
                const float* const hb5 = hw[parA] + ty * BW + tx;
#pragma unroll
                for (int c = 0; c < 5; ++c) h5[c] = hb5[c * HWC];
            } else {
#pragma unroll
                for (int c = 0; c < 5; ++c) h5[c] = 0.0f;
            }
#pragma unroll
            for (int c = 0; c < 5; ++c) sa[c] += h5[c];
            const int dout = d0 + t - 8;
            if (t >= 8 && dout < Dd) {
                const float cross = sa[4] - sa[0] * sa[1] * INV_WV;
                const float iv    = sa[2] - sa[0] * sa[0] * INV_WV;
                const float jv    = sa[3] - sa[1] * sa[1] * INV_WV;
                acc += (cross * cross) * __builtin_amdgcn_rcpf(iv * jv + 1e-5f);
            }
#pragma unroll
            for (int c = 0; c < 5; ++c) sa[c] -= hist[(u + 1) % 9][c];
#pragma unroll
            for (int c = 0; c < 5; ++c) hist[u][c] = h5[c];

            bar_lds();
        }
    }
#undef ISSUE
#undef STAGE_A
#undef STAGE_A2

    // ---- block reduction + global atomic (pre-scaled) ----
    red[tid] = acc;
    __syncthreads();
    for (int off = NT / 2; off > 0; off >>= 1) {
        if (tid < off) red[tid] += red[tid + off];
        __syncthreads();
    }
    if (tid == 0) atomicAdd(out, red[0] * NEG_INV_TOTAL);
}

extern "C" void kernel_launch(void* const* d_in, const int* in_sizes, int n_in,
                              void* d_out, int out_size, void* d_ws, size_t ws_size,
                              hipStream_t stream) {
    const float* I = (const float*)d_in[0];
    const float* J = (const float*)d_in[1];
    float* out = (float*)d_out;

    hipMemsetAsync(d_out, 0, sizeof(float), stream);   // stream-ordered, graph-safe
    k_ncc<<<NBLK, NT, 0, stream>>>(I, J, out);
}